// Round 8
// baseline (413.147 us; speedup 1.0000x reference)
//
#include <hip/hip_runtime.h>
#include <hip/hip_bf16.h>

// Problem constants
#define Bq   16
#define Nq   1024
#define Cq   256
#define NHq  8
#define DHq  32
#define HIDq 1024
#define BNq  (Bq * Nq)   // 16384 tokens

typedef float f32x4 __attribute__((ext_vector_type(4)));
typedef short bf16x8 __attribute__((ext_vector_type(8)));
typedef short bf16x4 __attribute__((ext_vector_type(4)));
typedef unsigned short ushort_t;

__device__ __forceinline__ unsigned int f2bf(float f) {   // RNE
    unsigned int u = __builtin_bit_cast(unsigned int, f);
    u = (u + 0x7fffu + ((u >> 16) & 1u)) >> 16;
    return u & 0xffffu;
}
// pack two floats -> two bf16 (round-half-up) in one dword via v_perm
__device__ __forceinline__ unsigned int packbf2(float a, float b) {
    unsigned int ua = __builtin_bit_cast(unsigned int, a) + 0x8000u;
    unsigned int ub = __builtin_bit_cast(unsigned int, b) + 0x8000u;
    return __builtin_amdgcn_perm(ub, ua, 0x07060302);
}
// branch-free tanh-approx GELU: x - x/(1+e^{2y}), y = 0.79788456(x+0.044715x^3)
__device__ __forceinline__ float gelu_t(float x) {
    float y = x * (0.7978845608028654f + 0.035677408136300125f * x * x);
    float e = __builtin_amdgcn_exp2f(y * 2.8853900817779268f);
    return x - x / (1.f + e);
}

typedef __attribute__((address_space(1))) const unsigned int* gas_u32;
typedef __attribute__((address_space(3))) unsigned int* las_u32;
__device__ __forceinline__ void gload16(const void* g, void* l) {
    __builtin_amdgcn_global_load_lds((gas_u32)g, (las_u32)l, 16, 0, 0);
}

// ---------------------------------------------------------------------------
// Fused fp32 -> bf16 casts: 9 segments in one dispatch.
// ---------------------------------------------------------------------------
struct CastSeg { const float* src; ushort_t* dst; int nblk; int n; };
struct CastArgs { CastSeg s[9]; };

__global__ __launch_bounds__(256) void castm(CastArgs a) {
    int bid = blockIdx.x;
    int seg = 0, acc = 0;
    for (seg = 0; seg < 9; seg++) {
        if (bid < acc + a.s[seg].nblk) break;
        acc += a.s[seg].nblk;
    }
    const CastSeg sg = a.s[seg];
    int i = (bid - acc) * 1024 + threadIdx.x * 4;
    if (i < sg.n) {
        float4 v = *(const float4*)(sg.src + i);
        uint2 u;
        u.x = packbf2(v.x, v.y);
        u.y = packbf2(v.z, v.w);
        *(uint2*)(sg.dst + i) = u;
    }
}

// ---------------------------------------------------------------------------
// LayerNorm over C=256 -> bf16. One wave per token, 4 tokens per block.
// ---------------------------------------------------------------------------
__global__ __launch_bounds__(256) void ln_kernel(const float* __restrict__ X,
                                                 const float* __restrict__ w,
                                                 const float* __restrict__ b,
                                                 ushort_t* __restrict__ Y) {
    int wave = threadIdx.x >> 6, lane = threadIdx.x & 63;
    int t = blockIdx.x * 4 + wave;
    float4 v = *(const float4*)(X + (size_t)t * Cq + lane * 4);
    float s = v.x + v.y + v.z + v.w;
#pragma unroll
    for (int d = 1; d < 64; d <<= 1) s += __shfl_xor(s, d);
    float mean = s * (1.f / 256.f);
    float4 dv = {v.x - mean, v.y - mean, v.z - mean, v.w - mean};
    float q = dv.x * dv.x + dv.y * dv.y + dv.z * dv.z + dv.w * dv.w;
#pragma unroll
    for (int d = 1; d < 64; d <<= 1) q += __shfl_xor(q, d);
    float rs = rsqrtf(q * (1.f / 256.f) + 1e-5f);
    float4 wv = *(const float4*)(w + lane * 4);
    float4 bv = *(const float4*)(b + lane * 4);
    uint2 u;
    u.x = packbf2(dv.x * rs * wv.x + bv.x, dv.y * rs * wv.y + bv.y);
    u.y = packbf2(dv.z * rs * wv.z + bv.z, dv.w * rs * wv.w + bv.w);
    *(uint2*)(Y + (size_t)t * Cq + lane * 4) = u;
}

// ---------------------------------------------------------------------------
// MFMA GEMM with global_load_lds staging, fragment-ordered LDS (unchanged r6).
// ---------------------------------------------------------------------------
template <int OMODE, bool GELU_, bool RESID, int KT>
__global__ __launch_bounds__(256) void mgemm(const ushort_t* __restrict__ A,
                                             const ushort_t* __restrict__ W,
                                             const float* __restrict__ bias,
                                             const float* __restrict__ R,
                                             void* __restrict__ OutP,
                                             int M, int Nn) {
    __shared__ __align__(16) ushort_t Al[4096];   // 4 chunks x 128 rows x 8
    __shared__ __align__(16) ushort_t Bl[4096];
    int m0 = blockIdx.x * 128, n0 = blockIdx.y * 128;
    int tid = threadIdx.x;
    int w = tid >> 6, lane = tid & 63;
    int l15 = lane & 15, quad = lane >> 4;
    int wrow = w >> 1, wcol = w & 1;

    f32x4 acc[4][4];
#pragma unroll
    for (int i = 0; i < 4; i++)
#pragma unroll
        for (int j = 0; j < 4; j++) acc[i][j] = (f32x4){0.f, 0.f, 0.f, 0.f};

    const ushort_t* gA0 = A + (size_t)(m0 + lane) * KT + w * 8;
    const ushort_t* gA1 = A + (size_t)(m0 + 64 + lane) * KT + w * 8;
    const ushort_t* gB0 = W + (size_t)(n0 + lane) * KT + w * 8;
    const ushort_t* gB1 = W + (size_t)(n0 + 64 + lane) * KT + w * 8;
    ushort_t* lA0 = &Al[(w * 128) * 8];
    ushort_t* lA1 = &Al[(w * 128 + 64) * 8];
    ushort_t* lB0 = &Bl[(w * 128) * 8];
    ushort_t* lB1 = &Bl[(w * 128 + 64) * 8];

#pragma unroll
    for (int k0 = 0; k0 < KT; k0 += 32) {
        gload16(gA0 + k0, lA0);
        gload16(gA1 + k0, lA1);
        gload16(gB0 + k0, lB0);
        gload16(gB1 + k0, lB1);
        __syncthreads();   // drains vmcnt -> DMA data visible

        bf16x8 aF[4], bF[4];
#pragma unroll
        for (int i = 0; i < 4; i++)
            aF[i] = *(const bf16x8*)&Al[(quad * 128 + wrow * 64 + i * 16 + l15) * 8];
#pragma unroll
        for (int j = 0; j < 4; j++)
            bF[j] = *(const bf16x8*)&Bl[(quad * 128 + wcol * 64 + j * 16 + l15) * 8];
#pragma unroll
        for (int i = 0; i < 4; i++)
#pragma unroll
            for (int j = 0; j < 4; j++)   // swapped: C^T -> n on reg axis
                acc[i][j] = __builtin_amdgcn_mfma_f32_16x16x32_bf16(bF[j], aF[i], acc[i][j], 0, 0, 0);
        __syncthreads();   // protect LDS before next DMA overwrite
    }

#pragma unroll
    for (int i = 0; i < 4; i++) {
        int mg = m0 + wrow * 64 + i * 16 + l15;
#pragma unroll
        for (int j = 0; j < 4; j++) {
            int ng = n0 + wcol * 64 + j * 16 + quad * 4;
            if (ng >= Nn) continue;
            f32x4 rv = acc[i][j];
            if constexpr (OMODE == 1) {
                int which = ng >> 8;
                int h = (ng >> 5) & 7;
                int d = ng & 31;
                int bb = mg >> 10, nn = mg & 1023;
                ushort_t* qb = (ushort_t*)OutP;
                if (which == 2) {          // V transposed: [bh][d][n]
                    size_t dst = 2 * (size_t)BNq * Cq +
                                 ((size_t)(bb * 8 + h) * 32 + d) * 1024 + nn;
#pragma unroll
                    for (int r = 0; r < 4; r++)
                        qb[dst + (size_t)r * 1024] = (ushort_t)f2bf(rv[r]);
                } else {
                    if (which == 0) {
                        const float sc = 0.17677669529663687f * 1.4426950408889634f;
                        rv[0] *= sc; rv[1] *= sc; rv[2] *= sc; rv[3] *= sc;
                    }
                    size_t dst = (size_t)which * ((size_t)BNq * Cq) +
                                 ((size_t)(bb * 8 + h) * 1024 + nn) * 32 + d;
                    uint2 pk;
                    pk.x = packbf2(rv[0], rv[1]);
                    pk.y = packbf2(rv[2], rv[3]);
                    *(uint2*)(qb + dst) = pk;
                }
            } else {
                if (bias) {
                    float4 bv = *(const float4*)(bias + ng);
                    rv[0] += bv.x; rv[1] += bv.y; rv[2] += bv.z; rv[3] += bv.w;
                }
                if (GELU_) {
#pragma unroll
                    for (int r = 0; r < 4; r++) rv[r] = gelu_t(rv[r]);
                }
                if constexpr (OMODE == 2) {
                    uint2 pk;
                    pk.x = packbf2(rv[0], rv[1]);
                    pk.y = packbf2(rv[2], rv[3]);
                    *(uint2*)((ushort_t*)OutP + (size_t)mg * Nn + ng) = pk;
                } else {
                    if (RESID) {
                        float4 rr = *(const float4*)(R + (size_t)mg * Nn + ng);
                        rv[0] += rr.x; rv[1] += rr.y; rv[2] += rr.z; rv[3] += rr.w;
                    }
                    *(float4*)((float*)OutP + (size_t)mg * Nn + ng) =
                        make_float4(rv[0], rv[1], rv[2], rv[3]);
                }
            }
        }
    }
}

// ---------------------------------------------------------------------------
// MFMA flash attention v4: ZERO LDS, zero barriers, zero shuffles.
// Q,K bf16 [bh][1024][32] (Q pre-scaled by rsqrt(32)*log2e); V bf16 transposed
// [bh][32][1024]. grid (128 bh, 8 q-tiles of 128), 256 thr = 4 waves x 32 q.
// Per 64-key iter: S^T = K·Q^T via 16x16x32 MFMA. The S^T C-layout
// (row=key=quad*4+r, col=q=l15) IS the 16x16x16 B-fragment layout, so PV is
// computed as O^T = V^T · P^T with v_mfma_f32_16x16x16_bf16 — P^T packs
// straight from C regs into the B operand. Row sums via ones-A MFMA (osum's
// C-layout gives every lane the sum for its own q=l15; no shuffle).
// ---------------------------------------------------------------------------
__global__ __launch_bounds__(256) void attn_mfma(const ushort_t* __restrict__ Qb,
                                                 const ushort_t* __restrict__ Kb,
                                                 const ushort_t* __restrict__ Vtg,
                                                 ushort_t* __restrict__ o) {
    int bh = blockIdx.x;
    int b = bh >> 3, h = bh & 7;
    int q0 = blockIdx.y * 128;
    int tid = threadIdx.x;
    int wave = tid >> 6, lane = tid & 63;
    int l15 = lane & 15, quad = lane >> 4;

    const size_t hb = (size_t)bh * 32768;

    bf16x8 qfrag[2];
#pragma unroll
    for (int g = 0; g < 2; g++)
        qfrag[g] = *(const bf16x8*)(Qb + hb + (size_t)(q0 + wave * 32 + g * 16 + l15) * 32 + quad * 8);

    // K frag pointer: A[m=key=l15][k=d=quad*8+j]  (+ (kt*64+kg*16)*32)
    const ushort_t* kfp = Kb + hb + (size_t)l15 * 32 + quad * 8;
    // V^T A-frag (16x16x16): A[m=d][k=key=quad*4+j]; halves d=l15, d=l15+16
    const ushort_t* vfp0 = Vtg + hb + (size_t)l15 * 1024 + quad * 4;
    const ushort_t* vfp1 = Vtg + hb + (size_t)(l15 + 16) * 1024 + quad * 4;

    bf16x4 onesA;
#pragma unroll
    for (int i = 0; i < 4; i++) onesA[i] = (short)0x3F80;   // bf16 1.0

    f32x4 oa[2][2];   // [g][d-half], C: row=d(quad*4+r), col=q(l15)
#pragma unroll
    for (int g = 0; g < 2; g++)
#pragma unroll
        for (int t = 0; t < 2; t++) oa[g][t] = (f32x4){0.f, 0.f, 0.f, 0.f};
    f32x4 osum[2] = {(f32x4){0.f, 0.f, 0.f, 0.f}, (f32x4){0.f, 0.f, 0.f, 0.f}};

    // prefetch kt=0 fragments
    bf16x8 kf[4];
    bf16x4 vf[4][2];
#pragma unroll
    for (int kg = 0; kg < 4; kg++) {
        kf[kg] = *(const bf16x8*)(kfp + (size_t)(kg * 16) * 32);
        vf[kg][0] = *(const bf16x4*)(vfp0 + kg * 16);
        vf[kg][1] = *(const bf16x4*)(vfp1 + kg * 16);
    }

    for (int kt = 0; kt < 16; kt++) {
        bf16x8 kfn[4];
        bf16x4 vfn[4][2];
        if (kt < 15) {
#pragma unroll
            for (int kg = 0; kg < 4; kg++) {
                kfn[kg] = *(const bf16x8*)(kfp + (size_t)((kt + 1) * 64 + kg * 16) * 32);
                vfn[kg][0] = *(const bf16x4*)(vfp0 + (kt + 1) * 64 + kg * 16);
                vfn[kg][1] = *(const bf16x4*)(vfp1 + (kt + 1) * 64 + kg * 16);
            }
        }
        const f32x4 z = {0.f, 0.f, 0.f, 0.f};
#pragma unroll
        for (int kg = 0; kg < 4; kg++) {
#pragma unroll
            for (int g = 0; g < 2; g++) {
                f32x4 st = __builtin_amdgcn_mfma_f32_16x16x32_bf16(kf[kg], qfrag[g], z, 0, 0, 0);
                float e0 = __builtin_amdgcn_exp2f(st[0]);
                float e1 = __builtin_amdgcn_exp2f(st[1]);
                float e2 = __builtin_amdgcn_exp2f(st[2]);
                float e3 = __builtin_amdgcn_exp2f(st[3]);
                uint2 pk;
                pk.x = packbf2(e0, e1);
                pk.y = packbf2(e2, e3);
                bf16x4 pB = __builtin_bit_cast(bf16x4, pk);   // P^T B-frag
                oa[g][0] = __builtin_amdgcn_mfma_f32_16x16x16bf16_1k(vf[kg][0], pB, oa[g][0], 0, 0, 0);
                oa[g][1] = __builtin_amdgcn_mfma_f32_16x16x16bf16_1k(vf[kg][1], pB, oa[g][1], 0, 0, 0);
                osum[g]  = __builtin_amdgcn_mfma_f32_16x16x16bf16_1k(onesA, pB, osum[g], 0, 0, 0);
            }
        }
#pragma unroll
        for (int kg = 0; kg < 4; kg++) {
            kf[kg] = kfn[kg];
            vf[kg][0] = vfn[kg][0];
            vf[kg][1] = vfn[kg][1];
        }
    }

    // lane holds O^T[d=quad*4+r (+16*half)][q=l15]; osum lane-local for q=l15
#pragma unroll
    for (int g = 0; g < 2; g++) {
        float inv = 1.f / osum[g][0];
        int q = q0 + wave * 32 + g * 16 + l15;
        ushort_t* orow = o + ((size_t)(b * 1024 + q)) * 256 + h * 32;
        uint2 p0, p1;
        p0.x = packbf2(oa[g][0][0] * inv, oa[g][0][1] * inv);
        p0.y = packbf2(oa[g][0][2] * inv, oa[g][0][3] * inv);
        p1.x = packbf2(oa[g][1][0] * inv, oa[g][1][1] * inv);
        p1.y = packbf2(oa[g][1][2] * inv, oa[g][1][3] * inv);
        *(uint2*)(orow + quad * 4) = p0;
        *(uint2*)(orow + 16 + quad * 4) = p1;
    }
}

// ---------------------------------------------------------------------------
// Deformable gather -> bf16. One block per token, thread = (h=tid>>5, d=tid&31).
// ---------------------------------------------------------------------------
__global__ __launch_bounds__(256) void deform_kernel(const float* __restrict__ ref,
                                                     const float* __restrict__ off,
                                                     const float* __restrict__ awl,
                                                     const float* __restrict__ v,
                                                     ushort_t* __restrict__ out) {
    int t = blockIdx.x;
    int b = t >> 10;
    int tid = threadIdx.x;
    int h = tid >> 5, d = tid & 31;

    float rx = ref[(size_t)t * 2 + 0];
    float ry = ref[(size_t)t * 2 + 1];
    const float* offr = off + (size_t)t * 64 + h * 8;
    const float* awr = awl + (size_t)t * 32 + h * 4;

    float L0 = awr[0], L1 = awr[1], L2 = awr[2], L3 = awr[3];
    float mm = fmaxf(fmaxf(L0, L1), fmaxf(L2, L3));
    float e0 = __expf(L0 - mm), e1 = __expf(L1 - mm), e2 = __expf(L2 - mm), e3 = __expf(L3 - mm);
    float inv = 1.f / (e0 + e1 + e2 + e3);
    float aw[4] = {e0 * inv, e1 * inv, e2 * inv, e3 * inv};

    const float* vb = v + (size_t)b * Nq * Cq + h * 32 + d;

    float s = 0.f;
#pragma unroll
    for (int p = 0; p < 4; p++) {
        float gx = rx * 32.f + offr[p * 2 + 0] - 0.5f;
        float gy = ry * 32.f + offr[p * 2 + 1] - 0.5f;
        float x0f = floorf(gx), y0f = floorf(gy);
        float lx = gx - x0f, ly = gy - y0f;
        int x0 = (int)x0f, y0 = (int)y0f;
        auto g = [&](int xi, int yi) -> float {
            if (xi < 0 || xi > 31 || yi < 0 || yi > 31) return 0.f;
            return vb[(size_t)(yi * 32 + xi) * Cq];
        };
        float sp = g(x0, y0) * (1.f - lx) * (1.f - ly)
                 + g(x0 + 1, y0) * lx * (1.f - ly)
                 + g(x0, y0 + 1) * (1.f - lx) * ly
                 + g(x0 + 1, y0 + 1) * lx * ly;
        s += aw[p] * sp;
    }
    out[(size_t)t * Cq + h * 32 + d] = (ushort_t)f2bf(s);
}

// ---------------------------------------------------------------------------
// Launch
// ---------------------------------------------------------------------------
extern "C" void kernel_launch(void* const* d_in, const int* in_sizes, int n_in,
                              void* d_out, int out_size, void* d_ws, size_t ws_size,
                              hipStream_t stream) {
    const size_t S = (size_t)BNq * Cq;  // 4,194,304
    float* ws = (float*)d_ws;
    float* X = ws;                                  // [0, S) residual fp32
    ushort_t* Ybf = (ushort_t*)(ws + S);            // [S, 1.5S)
    ushort_t* Wbf = (ushort_t*)(ws + S + S / 2);    // [1.5S, 2S)

    ushort_t* Wqkv   = Wbf;
    ushort_t* Wproj  = Wbf + 196608;
    ushort_t* Woff   = Wbf + 262144;
    ushort_t* Waw    = Wbf + 278528;
    ushort_t* Wvproj = Wbf + 286720;
    ushort_t* Woproj = Wbf + 352256;
    ushort_t* Wfc1   = Wbf + 417792;
    ushort_t* Wfc2   = Wbf + 679936;

    ushort_t* QKVbf = (ushort_t*)(ws + 2 * S);              // Q,K,V^T: [2S, 3.5S)
    ushort_t* O1bf  = (ushort_t*)(ws + 2 * S + 3 * S / 2);  // [3.5S, 4S)
    float* Vb   = ws + 2 * S + S / 2;                       // [2.5S, 3.5S)
    float* OffB = ws + 2 * S + 3 * S / 2;                   // [3.5S, 3.75S)
    float* AwB  = OffB + (size_t)BNq * 64;                  // [3.75S, 3.875S)
    ushort_t* Sbbf = (ushort_t*)(AwB + (size_t)BNq * 32);   // [3.875S, 4.375S)
    ushort_t* Hbbf = (ushort_t*)(ws + 2 * S);               // [2S, 4S)
    ushort_t* Valbf = (ushort_t*)(ws + 9 * S / 2);          // [4.5S, 5S)

    auto fp = [&](int i) { return (const float*)d_in[i]; };
    const float* x_in = fp(0);

    // ---- all fp32->bf16 casts in one dispatch ----
    CastArgs ca;
    ca.s[0] = {fp(9),  Wqkv,   192, 196608};
    ca.s[1] = {fp(10), Wproj,  64,  65536};
    ca.s[2] = {fp(12), Woff,   16,  16384};
    ca.s[3] = {fp(14), Waw,    8,   8192};
    ca.s[4] = {fp(16), Wvproj, 64,  65536};
    ca.s[5] = {fp(18), Woproj, 64,  65536};
    ca.s[6] = {fp(20), Wfc1,   256, 262144};
    ca.s[7] = {fp(22), Wfc2,   256, 262144};
    ca.s[8] = {fp(2),  Valbf,  4096, (int)S};
    castm<<<5016, 256, 0, stream>>>(ca);

    // ---- stage 1: self-attention ----
    ln_kernel<<<BNq / 4, 256, 0, stream>>>(x_in, fp(3), fp(4), Ybf);
    mgemm<1, false, false, 256><<<dim3(128, 6), 256, 0, stream>>>(
        Ybf, Wqkv, nullptr, nullptr, QKVbf, BNq, 768);
    attn_mfma<<<dim3(128, 8), 256, 0, stream>>>(
        QKVbf, QKVbf + S, QKVbf + 2 * S, O1bf);
    mgemm<0, false, true, 256><<<dim3(128, 2), 256, 0, stream>>>(
        O1bf, Wproj, fp(11), x_in, X, BNq, 256);

    // ---- stage 2: deformable attention ----
    ln_kernel<<<BNq / 4, 256, 0, stream>>>(X, fp(5), fp(6), Ybf);
    mgemm<0, false, false, 256><<<dim3(128, 2), 256, 0, stream>>>(
        Valbf, Wvproj, fp(17), nullptr, Vb, BNq, 256);
    mgemm<0, false, false, 256><<<dim3(128, 1), 256, 0, stream>>>(
        Ybf, Woff, fp(13), nullptr, OffB, BNq, 64);
    mgemm<0, false, false, 256><<<dim3(128, 1), 256, 0, stream>>>(
        Ybf, Waw, fp(15), nullptr, AwB, BNq, 32);
    deform_kernel<<<BNq, 256, 0, stream>>>(fp(1), OffB, AwB, Vb, Sbbf);
    mgemm<0, false, true, 256><<<dim3(128, 2), 256, 0, stream>>>(
        Sbbf, Woproj, fp(19), X, X, BNq, 256);

    // ---- stage 3: MLP ----
    ln_kernel<<<BNq / 4, 256, 0, stream>>>(X, fp(7), fp(8), Ybf);
    mgemm<2, true, false, 256><<<dim3(128, 8), 256, 0, stream>>>(
        Ybf, Wfc1, fp(21), nullptr, Hbbf, BNq, 1024);
    mgemm<0, false, true, 1024><<<dim3(128, 2), 256, 0, stream>>>(
        Hbbf, Wfc2, fp(23), X, d_out, BNq, 256);
}

// Round 9
// 342.560 us; speedup vs baseline: 1.2061x; 1.2061x over previous
//
#include <hip/hip_runtime.h>
#include <hip/hip_bf16.h>

// Problem constants
#define Bq   16
#define Nq   1024
#define Cq   256
#define NHq  8
#define DHq  32
#define HIDq 1024
#define BNq  (Bq * Nq)   // 16384 tokens

typedef float f32x4 __attribute__((ext_vector_type(4)));
typedef short bf16x8 __attribute__((ext_vector_type(8)));
typedef unsigned short ushort_t;

__device__ __forceinline__ unsigned int f2bf(float f) {   // RNE
    unsigned int u = __builtin_bit_cast(unsigned int, f);
    u = (u + 0x7fffu + ((u >> 16) & 1u)) >> 16;
    return u & 0xffffu;
}
// pack two floats -> two bf16 (round-half-up) in one dword via v_perm
__device__ __forceinline__ unsigned int packbf2(float a, float b) {
    unsigned int ua = __builtin_bit_cast(unsigned int, a) + 0x8000u;
    unsigned int ub = __builtin_bit_cast(unsigned int, b) + 0x8000u;
    return __builtin_amdgcn_perm(ub, ua, 0x07060302);
}
// branch-free tanh-approx GELU
__device__ __forceinline__ float gelu_t(float x) {
    float y = x * (0.7978845608028654f + 0.035677408136300125f * x * x);
    float e = __builtin_amdgcn_exp2f(y * 2.8853900817779268f);
    return x - x / (1.f + e);
}

typedef __attribute__((address_space(1))) const unsigned int* gas_u32;
typedef __attribute__((address_space(3))) unsigned int* las_u32;
__device__ __forceinline__ void gload16(const void* g, void* l) {
    __builtin_amdgcn_global_load_lds((gas_u32)g, (las_u32)l, 16, 0, 0);
}

// ---------------------------------------------------------------------------
// Fused fp32 -> bf16 casts: 9 segments in one dispatch.
// ---------------------------------------------------------------------------
struct CastSeg { const float* src; ushort_t* dst; int nblk; int n; };
struct CastArgs { CastSeg s[9]; };

__global__ __launch_bounds__(256) void castm(CastArgs a) {
    int bid = blockIdx.x;
    int seg = 0, acc = 0;
    for (seg = 0; seg < 9; seg++) {
        if (bid < acc + a.s[seg].nblk) break;
        acc += a.s[seg].nblk;
    }
    const CastSeg sg = a.s[seg];
    int i = (bid - acc) * 1024 + threadIdx.x * 4;
    if (i < sg.n) {
        float4 v = *(const float4*)(sg.src + i);
        uint2 u;
        u.x = packbf2(v.x, v.y);
        u.y = packbf2(v.z, v.w);
        *(uint2*)(sg.dst + i) = u;
    }
}

// ---------------------------------------------------------------------------
// LayerNorm over C=256 -> bf16. One wave per token, 4 tokens per block.
// ---------------------------------------------------------------------------
__global__ __launch_bounds__(256) void ln_kernel(const float* __restrict__ X,
                                                 const float* __restrict__ w,
                                                 const float* __restrict__ b,
                                                 ushort_t* __restrict__ Y) {
    int wave = threadIdx.x >> 6, lane = threadIdx.x & 63;
    int t = blockIdx.x * 4 + wave;
    float4 v = *(const float4*)(X + (size_t)t * Cq + lane * 4);
    float s = v.x + v.y + v.z + v.w;
#pragma unroll
    for (int d = 1; d < 64; d <<= 1) s += __shfl_xor(s, d);
    float mean = s * (1.f / 256.f);
    float4 dv = {v.x - mean, v.y - mean, v.z - mean, v.w - mean};
    float q = dv.x * dv.x + dv.y * dv.y + dv.z * dv.z + dv.w * dv.w;
#pragma unroll
    for (int d = 1; d < 64; d <<= 1) q += __shfl_xor(q, d);
    float rs = rsqrtf(q * (1.f / 256.f) + 1e-5f);
    float4 wv = *(const float4*)(w + lane * 4);
    float4 bv = *(const float4*)(b + lane * 4);
    uint2 u;
    u.x = packbf2(dv.x * rs * wv.x + bv.x, dv.y * rs * wv.y + bv.y);
    u.y = packbf2(dv.z * rs * wv.z + bv.z, dv.w * rs * wv.w + bv.w);
    *(uint2*)(Y + (size_t)t * Cq + lane * 4) = u;
}

// ---------------------------------------------------------------------------
// MFMA GEMM, global_load_lds staging, fragment-ordered LDS, BK=64
// (32 MFMAs between barriers — halves barrier-drain count vs BK=32).
// LDS: 8 chunks x 128 rows x 8 ushorts per operand (32 KB total).
// Chunk c holds k = k0 + (c&3)*8 + (c>>2)*32; wave w stages chunks {w, w+4}.
// MFMA operands swapped (C^T): thread holds 4 consecutive n-values.
// OMODE 0: fp32 out (+bias/GELU/residual); OMODE 1: qkv -> bf16 head-major
//          (Q scaled by rsqrt(32)*log2e, V transposed [bh][32][1024]);
// OMODE 2: bf16 out; OMODE 3: fused off/aw (ng<64 -> OffB w/ bias, else AwB
//          w/ R-as-bias; AwB = OutP + BN*64).
// ---------------------------------------------------------------------------
template <int OMODE, bool GELU_, bool RESID, int KT>
__global__ __launch_bounds__(256) void mgemm(const ushort_t* __restrict__ A,
                                             const ushort_t* __restrict__ W,
                                             const float* __restrict__ bias,
                                             const float* __restrict__ R,
                                             void* __restrict__ OutP,
                                             int M, int Nn) {
    __shared__ __align__(16) ushort_t Al[8192];
    __shared__ __align__(16) ushort_t Bl[8192];
    int m0 = blockIdx.x * 128, n0 = blockIdx.y * 128;
    int tid = threadIdx.x;
    int w = tid >> 6, lane = tid & 63;
    int l15 = lane & 15, quad = lane >> 4;
    int wrow = w >> 1, wcol = w & 1;

    f32x4 acc[4][4];
#pragma unroll
    for (int i = 0; i < 4; i++)
#pragma unroll
        for (int j = 0; j < 4; j++) acc[i][j] = (f32x4){0.f, 0.f, 0.f, 0.f};

    const ushort_t* gA0 = A + (size_t)(m0 + lane) * KT + w * 8;
    const ushort_t* gA1 = A + (size_t)(m0 + 64 + lane) * KT + w * 8;
    const ushort_t* gB0 = W + (size_t)(n0 + lane) * KT + w * 8;
    const ushort_t* gB1 = W + (size_t)(n0 + 64 + lane) * KT + w * 8;
    ushort_t* lA0  = &Al[(w * 128) * 8];
    ushort_t* lA1  = &Al[(w * 128 + 64) * 8];
    ushort_t* lA0h = &Al[((w + 4) * 128) * 8];
    ushort_t* lA1h = &Al[((w + 4) * 128 + 64) * 8];
    ushort_t* lB0  = &Bl[(w * 128) * 8];
    ushort_t* lB1  = &Bl[(w * 128 + 64) * 8];
    ushort_t* lB0h = &Bl[((w + 4) * 128) * 8];
    ushort_t* lB1h = &Bl[((w + 4) * 128 + 64) * 8];

#pragma unroll
    for (int k0 = 0; k0 < KT; k0 += 64) {
        gload16(gA0 + k0, lA0);
        gload16(gA1 + k0, lA1);
        gload16(gA0 + k0 + 32, lA0h);
        gload16(gA1 + k0 + 32, lA1h);
        gload16(gB0 + k0, lB0);
        gload16(gB1 + k0, lB1);
        gload16(gB0 + k0 + 32, lB0h);
        gload16(gB1 + k0 + 32, lB1h);
        __syncthreads();   // drains vmcnt -> DMA data visible

#pragma unroll
        for (int ks = 0; ks < 2; ks++) {
            bf16x8 aF[4], bF[4];
#pragma unroll
            for (int i = 0; i < 4; i++)
                aF[i] = *(const bf16x8*)&Al[((ks * 4 + quad) * 128 + wrow * 64 + i * 16 + l15) * 8];
#pragma unroll
            for (int j = 0; j < 4; j++)
                bF[j] = *(const bf16x8*)&Bl[((ks * 4 + quad) * 128 + wcol * 64 + j * 16 + l15) * 8];
#pragma unroll
            for (int i = 0; i < 4; i++)
#pragma unroll
                for (int j = 0; j < 4; j++)
                    acc[i][j] = __builtin_amdgcn_mfma_f32_16x16x32_bf16(bF[j], aF[i], acc[i][j], 0, 0, 0);
        }
        __syncthreads();   // protect LDS before next DMA overwrite
    }

#pragma unroll
    for (int i = 0; i < 4; i++) {
        int mg = m0 + wrow * 64 + i * 16 + l15;
#pragma unroll
        for (int j = 0; j < 4; j++) {
            int ng = n0 + wcol * 64 + j * 16 + quad * 4;
            f32x4 rv = acc[i][j];
            if constexpr (OMODE == 1) {
                int which = ng >> 8;
                int h = (ng >> 5) & 7;
                int d = ng & 31;
                int bb = mg >> 10, nn = mg & 1023;
                ushort_t* qb = (ushort_t*)OutP;
                if (which == 2) {          // V transposed: [bh][d][n]
                    size_t dst = 2 * (size_t)BNq * Cq +
                                 ((size_t)(bb * 8 + h) * 32 + d) * 1024 + nn;
#pragma unroll
                    for (int r = 0; r < 4; r++)
                        qb[dst + (size_t)r * 1024] = (ushort_t)f2bf(rv[r]);
                } else {
                    if (which == 0) {
                        const float sc = 0.17677669529663687f * 1.4426950408889634f;
                        rv[0] *= sc; rv[1] *= sc; rv[2] *= sc; rv[3] *= sc;
                    }
                    size_t dst = (size_t)which * ((size_t)BNq * Cq) +
                                 ((size_t)(bb * 8 + h) * 1024 + nn) * 32 + d;
                    uint2 pk;
                    pk.x = packbf2(rv[0], rv[1]);
                    pk.y = packbf2(rv[2], rv[3]);
                    *(uint2*)(qb + dst) = pk;
                }
            } else if constexpr (OMODE == 3) {
                if (ng >= 96) continue;
                if (ng < 64) {
                    float4 bv = *(const float4*)(bias + ng);
                    rv[0] += bv.x; rv[1] += bv.y; rv[2] += bv.z; rv[3] += bv.w;
                    *(float4*)((float*)OutP + (size_t)mg * 64 + ng) =
                        make_float4(rv[0], rv[1], rv[2], rv[3]);
                } else {
                    float4 bv = *(const float4*)(R + (ng - 64));
                    rv[0] += bv.x; rv[1] += bv.y; rv[2] += bv.z; rv[3] += bv.w;
                    *(float4*)((float*)OutP + (size_t)BNq * 64 + (size_t)mg * 32 + (ng - 64)) =
                        make_float4(rv[0], rv[1], rv[2], rv[3]);
                }
            } else {
                if (bias) {
                    float4 bv = *(const float4*)(bias + ng);
                    rv[0] += bv.x; rv[1] += bv.y; rv[2] += bv.z; rv[3] += bv.w;
                }
                if (GELU_) {
#pragma unroll
                    for (int r = 0; r < 4; r++) rv[r] = gelu_t(rv[r]);
                }
                if constexpr (OMODE == 2) {
                    uint2 pk;
                    pk.x = packbf2(rv[0], rv[1]);
                    pk.y = packbf2(rv[2], rv[3]);
                    *(uint2*)((ushort_t*)OutP + (size_t)mg * Nn + ng) = pk;
                } else {
                    if (RESID) {
                        float4 rr = *(const float4*)(R + (size_t)mg * Nn + ng);
                        rv[0] += rr.x; rv[1] += rr.y; rv[2] += rr.z; rv[3] += rr.w;
                    }
                    *(float4*)((float*)OutP + (size_t)mg * Nn + ng) =
                        make_float4(rv[0], rv[1], rv[2], rv[3]);
                }
            }
        }
    }
}

// ---------------------------------------------------------------------------
// MFMA flash attention (r6 version — measured best, 42.8 us).
// Q,K bf16 [bh][1024][32] (Q pre-scaled by rsqrt(32)*log2e); V bf16 transposed
// [bh][32][1024]. grid (128 bh, 8 q-tiles of 128), 256 thr = 4 waves x 32 q.
// ---------------------------------------------------------------------------
__global__ __launch_bounds__(256) void attn_mfma(const ushort_t* __restrict__ Qb,
                                                 const ushort_t* __restrict__ Kb,
                                                 const ushort_t* __restrict__ Vtg,
                                                 ushort_t* __restrict__ o) {
    int bh = blockIdx.x;
    int b = bh >> 3, h = bh & 7;
    int q0 = blockIdx.y * 128;
    int tid = threadIdx.x;
    int wave = tid >> 6, lane = tid & 63;
    int l15 = lane & 15, quad = lane >> 4;

    __shared__ __align__(16) ushort_t Ks[64][40];     // [key][d]
    __shared__ __align__(16) ushort_t Vs[32][88];     // [d][key]
    __shared__ __align__(16) ushort_t Ps[4][32][72];  // per wave [q][key]

    const size_t hb = (size_t)bh * 32768;

    bf16x8 qfrag[2];
#pragma unroll
    for (int g = 0; g < 2; g++)
        qfrag[g] = *(const bf16x8*)(Qb + hb + (size_t)(q0 + wave * 32 + g * 16 + l15) * 32 + quad * 8);

    f32x4 oa[2][2];
#pragma unroll
    for (int g = 0; g < 2; g++)
#pragma unroll
        for (int t = 0; t < 2; t++) oa[g][t] = (f32x4){0.f, 0.f, 0.f, 0.f};
    float lsum[2] = {0.f, 0.f};

    int krow = tid >> 2, kch = tid & 3;
    int vrow = tid >> 3, vch = tid & 7;
    const ushort_t* kgp = Kb + hb + (size_t)krow * 32 + kch * 8;
    const ushort_t* vgp = Vtg + hb + (size_t)vrow * 1024 + vch * 8;

    for (int kt = 0; kt < 16; kt++) {
        __syncthreads();
        *(bf16x8*)&Ks[krow][kch * 8] = *(const bf16x8*)(kgp + kt * 64 * 32);
        *(bf16x8*)&Vs[vrow][vch * 8] = *(const bf16x8*)(vgp + kt * 64);
        __syncthreads();

        bf16x8 kf[4];
#pragma unroll
        for (int kg = 0; kg < 4; kg++)
            kf[kg] = *(const bf16x8*)&Ks[kg * 16 + l15][quad * 8];

        const f32x4 z = {0.f, 0.f, 0.f, 0.f};
#pragma unroll
        for (int g = 0; g < 2; g++) {
#pragma unroll
            for (int kg = 0; kg < 4; kg++) {
                f32x4 st = __builtin_amdgcn_mfma_f32_16x16x32_bf16(kf[kg], qfrag[g], z, 0, 0, 0);
                float e0 = __builtin_amdgcn_exp2f(st[0]);
                float e1 = __builtin_amdgcn_exp2f(st[1]);
                float e2 = __builtin_amdgcn_exp2f(st[2]);
                float e3 = __builtin_amdgcn_exp2f(st[3]);
                lsum[g] += (e0 + e1) + (e2 + e3);
                uint2 pk;
                pk.x = packbf2(e0, e1);
                pk.y = packbf2(e2, e3);
                *(uint2*)&Ps[wave][g * 16 + l15][kg * 16 + quad * 4] = pk;
            }
        }
#pragma unroll
        for (int c = 0; c < 2; c++) {
            bf16x8 vb0 = *(const bf16x8*)&Vs[l15][c * 32 + quad * 8];
            bf16x8 vb1 = *(const bf16x8*)&Vs[16 + l15][c * 32 + quad * 8];
#pragma unroll
            for (int g = 0; g < 2; g++) {
                bf16x8 pa = *(const bf16x8*)&Ps[wave][g * 16 + l15][c * 32 + quad * 8];
                oa[g][0] = __builtin_amdgcn_mfma_f32_16x16x32_bf16(pa, vb0, oa[g][0], 0, 0, 0);
                oa[g][1] = __builtin_amdgcn_mfma_f32_16x16x32_bf16(pa, vb1, oa[g][1], 0, 0, 0);
            }
        }
    }

#pragma unroll
    for (int g = 0; g < 2; g++) {
        float rs = lsum[g];
        rs += __shfl_xor(rs, 16);
        rs += __shfl_xor(rs, 32);
        lsum[g] = rs;
    }
#pragma unroll
    for (int g = 0; g < 2; g++) {
#pragma unroll
        for (int r = 0; r < 4; r++) {
            float inv = 1.f / __shfl(lsum[g], quad * 4 + r);
            int q = q0 + wave * 32 + g * 16 + quad * 4 + r;
            ushort_t* orow = o + ((size_t)(b * 1024 + q)) * 256 + h * 32;
            orow[l15] = (ushort_t)f2bf(oa[g][0][r] * inv);
            orow[l15 + 16] = (ushort_t)f2bf(oa[g][1][r] * inv);
        }
    }
}

// ---------------------------------------------------------------------------
// Deformable gather -> bf16. One block per token, thread = (h=tid>>5, d=tid&31).
// ---------------------------------------------------------------------------
__global__ __launch_bounds__(256) void deform_kernel(const float* __restrict__ ref,
                                                     const float* __restrict__ off,
                                                     const float* __restrict__ awl,
                                                     const float* __restrict__ v,
                                                     ushort_t* __restrict__ out) {
    int t = blockIdx.x;
    int b = t >> 10;
    int tid = threadIdx.x;
    int h = tid >> 5, d = tid & 31;

    float rx = ref[(size_t)t * 2 + 0];
    float ry = ref[(size_t)t * 2 + 1];
    const float* offr = off + (size_t)t * 64 + h * 8;
    const float* awr = awl + (size_t)t * 32 + h * 4;

    float L0 = awr[0], L1 = awr[1], L2 = awr[2], L3 = awr[3];
    float mm = fmaxf(fmaxf(L0, L1), fmaxf(L2, L3));
    float e0 = __expf(L0 - mm), e1 = __expf(L1 - mm), e2 = __expf(L2 - mm), e3 = __expf(L3 - mm);
    float inv = 1.f / (e0 + e1 + e2 + e3);
    float aw[4] = {e0 * inv, e1 * inv, e2 * inv, e3 * inv};

    const float* vb = v + (size_t)b * Nq * Cq + h * 32 + d;

    float s = 0.f;
#pragma unroll
    for (int p = 0; p < 4; p++) {
        float gx = rx * 32.f + offr[p * 2 + 0] - 0.5f;
        float gy = ry * 32.f + offr[p * 2 + 1] - 0.5f;
        float x0f = floorf(gx), y0f = floorf(gy);
        float lx = gx - x0f, ly = gy - y0f;
        int x0 = (int)x0f, y0 = (int)y0f;
        auto g = [&](int xi, int yi) -> float {
            if (xi < 0 || xi > 31 || yi < 0 || yi > 31) return 0.f;
            return vb[(size_t)(yi * 32 + xi) * Cq];
        };
        float sp = g(x0, y0) * (1.f - lx) * (1.f - ly)
                 + g(x0 + 1, y0) * lx * (1.f - ly)
                 + g(x0, y0 + 1) * (1.f - lx) * ly
                 + g(x0 + 1, y0 + 1) * lx * ly;
        s += aw[p] * sp;
    }
    out[(size_t)t * Cq + h * 32 + d] = (ushort_t)f2bf(s);
}

// ---------------------------------------------------------------------------
// Launch
// ---------------------------------------------------------------------------
extern "C" void kernel_launch(void* const* d_in, const int* in_sizes, int n_in,
                              void* d_out, int out_size, void* d_ws, size_t ws_size,
                              hipStream_t stream) {
    const size_t S = (size_t)BNq * Cq;  // 4,194,304
    float* ws = (float*)d_ws;
    float* X = ws;                                  // [0, S) residual fp32
    ushort_t* Ybf = (ushort_t*)(ws + S);            // [S, 1.5S)
    ushort_t* Wbf = (ushort_t*)(ws + S + S / 2);    // [1.5S, 2S)

    ushort_t* Wqkv   = Wbf;
    ushort_t* Wproj  = Wbf + 196608;
    ushort_t* Woff   = Wbf + 262144;   // off(64 rows) + aw(32 rows) contiguous
    ushort_t* Waw    = Wbf + 278528;
    ushort_t* Wvproj = Wbf + 286720;
    ushort_t* Woproj = Wbf + 352256;
    ushort_t* Wfc1   = Wbf + 417792;
    ushort_t* Wfc2   = Wbf + 679936;

    ushort_t* QKVbf = (ushort_t*)(ws + 2 * S);              // Q,K,V^T: [2S, 3.5S)
    ushort_t* O1bf  = (ushort_t*)(ws + 2 * S + 3 * S / 2);  // [3.5S, 4S)
    float* Vb   = ws + 2 * S + S / 2;                       // [2.5S, 3.5S)
    float* OffB = ws + 2 * S + 3 * S / 2;                   // [3.5S, 3.75S)
    float* AwB  = OffB + (size_t)BNq * 64;                  // [3.75S, 3.875S) (contiguous after OffB)
    ushort_t* Sbbf = (ushort_t*)(AwB + (size_t)BNq * 32);   // [3.875S, 4.375S)
    ushort_t* Hbbf = (ushort_t*)(ws + 2 * S);               // [2S, 4S)
    ushort_t* Valbf = (ushort_t*)(ws + 9 * S / 2);          // [4.5S, 5S)

    auto fp = [&](int i) { return (const float*)d_in[i]; };
    const float* x_in = fp(0);

    // ---- all fp32->bf16 casts in one dispatch ----
    CastArgs ca;
    ca.s[0] = {fp(9),  Wqkv,   192, 196608};
    ca.s[1] = {fp(10), Wproj,  64,  65536};
    ca.s[2] = {fp(12), Woff,   16,  16384};
    ca.s[3] = {fp(14), Waw,    8,   8192};
    ca.s[4] = {fp(16), Wvproj, 64,  65536};
    ca.s[5] = {fp(18), Woproj, 64,  65536};
    ca.s[6] = {fp(20), Wfc1,   256, 262144};
    ca.s[7] = {fp(22), Wfc2,   256, 262144};
    ca.s[8] = {fp(2),  Valbf,  4096, (int)S};
    castm<<<5016, 256, 0, stream>>>(ca);

    // ---- stage 1: self-attention ----
    ln_kernel<<<BNq / 4, 256, 0, stream>>>(x_in, fp(3), fp(4), Ybf);
    mgemm<1, false, false, 256><<<dim3(128, 6), 256, 0, stream>>>(
        Ybf, Wqkv, nullptr, nullptr, QKVbf, BNq, 768);
    attn_mfma<<<dim3(128, 8), 256, 0, stream>>>(
        QKVbf, QKVbf + S, QKVbf + 2 * S, O1bf);
    mgemm<0, false, true, 256><<<dim3(128, 2), 256, 0, stream>>>(
        O1bf, Wproj, fp(11), x_in, X, BNq, 256);

    // ---- stage 2: deformable attention ----
    ln_kernel<<<BNq / 4, 256, 0, stream>>>(X, fp(5), fp(6), Ybf);
    mgemm<0, false, false, 256><<<dim3(128, 2), 256, 0, stream>>>(
        Valbf, Wvproj, fp(17), nullptr, Vb, BNq, 256);
    mgemm<3, false, false, 256><<<dim3(128, 1), 256, 0, stream>>>(
        Ybf, Woff, fp(13), fp(15), OffB, BNq, 96);
    deform_kernel<<<BNq, 256, 0, stream>>>(fp(1), OffB, AwB, Vb, Sbbf);
    mgemm<0, false, true, 256><<<dim3(128, 2), 256, 0, stream>>>(
        Sbbf, Woproj, fp(19), X, X, BNq, 256);

    // ---- stage 3: MLP ----
    ln_kernel<<<BNq / 4, 256, 0, stream>>>(X, fp(7), fp(8), Ybf);
    mgemm<2, true, false, 256><<<dim3(128, 8), 256, 0, stream>>>(
        Ybf, Wfc1, fp(21), nullptr, Hbbf, BNq, 1024);
    mgemm<0, false, true, 1024><<<dim3(128, 2), 256, 0, stream>>>(
        Hbbf, Wfc2, fp(23), X, d_out, BNq, 256);
}